// Round 2
// baseline (184.622 us; speedup 1.0000x reference)
//
#include <hip/hip_runtime.h>
#include <hip/hip_cooperative_groups.h>
#include <math.h>

namespace cg = cooperative_groups;

#define WIDTH   1024
#define NROWS   8192        // N
#define NCOLS   8193        // N + 1 (bias in last column)
#define N_LAYERS 8

// Fused 7-layer MLP chain in one cooperative kernel.
// Grid = 256 blocks x 256 threads (1 block/CU, co-resident).
// Each wave (64 lanes) computes one output row per layer: 1024 waves = 1024 rows.
__global__ __launch_bounds__(256) void mlp_fused_kernel(
    const float* __restrict__ P,     // parameter_matrix, row-major (8192 x 8193)
    const float* __restrict__ x,     // input activation (1024)
    float* __restrict__ out,         // final output (1024)
    float* __restrict__ ws)          // workspace: 2 x 1024 floats ping-pong
{
    cg::grid_group grid = cg::this_grid();

    const int wave = threadIdx.x >> 6;
    const int lane = threadIdx.x & 63;
    const int row  = (blockIdx.x << 2) + wave;          // 0..1023

    float* h0 = ws;
    float* h1 = ws + WIDTH;

    const float* cur = x;
    for (int l = 1; l < N_LAYERS; ++l) {
        const bool last = (l == N_LAYERS - 1);
        float* dst = last ? out : ((l & 1) ? h0 : h1);

        const size_t rowbase = (size_t)(l * WIDTH + row) * (size_t)NCOLS;
        const float* __restrict__ wrow = P + rowbase + (size_t)(l - 1) * WIDTH;

        // 1024-element dot product: 16 coalesced dword loads per lane.
        // (row stride 8193 floats is odd -> not 16B aligned; scalar dwords
        //  are still fully coalesced, 256B per wave per instruction)
        float sum = 0.f;
        #pragma unroll
        for (int j = 0; j < 16; ++j) {
            const int idx = (j << 6) + lane;
            sum += wrow[idx] * cur[idx];
        }

        // wave64 butterfly reduce
        #pragma unroll
        for (int off = 32; off > 0; off >>= 1)
            sum += __shfl_xor(sum, off, 64);

        if (lane == 0) {
            float a = sum + P[rowbase + NROWS];          // + bias (col N)
            if (!last) {
                a = a / (1.f + __expf(-a));              // silu
            }
            dst[row] = a;
        }

        if (!last) grid.sync();                          // layer barrier (device-scope fence)
        cur = dst;
    }
}

extern "C" void kernel_launch(void* const* d_in, const int* in_sizes, int n_in,
                              void* d_out, int out_size, void* d_ws, size_t ws_size,
                              hipStream_t stream) {
    const float* P = (const float*)d_in[1];              // (8192, 8193)
    const float* x = (const float*)d_in[0];              // (1024,)
    float* out = (float*)d_out;                          // (1024,)
    float* ws  = (float*)d_ws;

    void* args[] = { (void*)&P, (void*)&x, (void*)&out, (void*)&ws };
    hipLaunchCooperativeKernel((const void*)mlp_fused_kernel,
                               dim3(256), dim3(256), args, 0, stream);
}

// Round 3
// 73.103 us; speedup vs baseline: 2.5255x; 2.5255x over previous
//
#include <hip/hip_runtime.h>
#include <math.h>

#define WIDTH    1024
#define NROWS    8192        // N
#define NCOLS    8193        // N + 1 (bias in last column)
#define N_LAYERS 8

#define NBLOCKS  64
#define TPB      1024
#define WAVES_PER_BLOCK (TPB / 64)   // 16 waves -> 16 rows per block

// Fused 7-layer MLP chain, one kernel, custom lightweight grid barrier.
// 64 blocks x 1024 threads = 1024 waves; wave g computes row g each layer.
__global__ __launch_bounds__(TPB) void mlp_fused_kernel(
    const float* __restrict__ P,      // parameter_matrix (8192 x 8193)
    const float* __restrict__ x,      // input (1024)
    float* __restrict__ out,          // output (1024)
    float* __restrict__ ws,           // 2 x 1024 floats ping-pong
    unsigned int* __restrict__ bar)   // 8 counters, zeroed before launch
{
    const int wid  = threadIdx.x >> 6;
    const int lane = threadIdx.x & 63;
    const int row  = blockIdx.x * WAVES_PER_BLOCK + wid;   // 0..1023

    float* h0 = ws;
    float* h1 = ws + WIDTH;

    const float* cur = x;
    for (int l = 1; l < N_LAYERS; ++l) {
        const bool last = (l == N_LAYERS - 1);
        float* dst = last ? out : ((l & 1) ? h0 : h1);

        const size_t rowbase = (size_t)(l * WIDTH + row) * (size_t)NCOLS;
        const float* __restrict__ wrow = P + rowbase + (size_t)(l - 1) * WIDTH;

        // 1024-elem dot product: 16 coalesced dword loads per lane
        // (row stride 8193 floats is odd -> rows not 16B-aligned; scalar
        //  dwords are still fully coalesced, 256B/wave/instruction)
        float sum = 0.f;
        #pragma unroll
        for (int j = 0; j < 16; ++j) {
            const int idx = (j << 6) + lane;
            sum += wrow[idx] * cur[idx];
        }

        // wave64 butterfly reduce
        #pragma unroll
        for (int off = 32; off > 0; off >>= 1)
            sum += __shfl_xor(sum, off, 64);

        if (lane == 0) {
            float a = sum + P[rowbase + NROWS];             // + bias
            if (!last) a = a / (1.f + __expf(-a));          // silu
            dst[row] = a;
        }

        if (!last) {
            // ---- lightweight grid barrier (agent scope, tight poll) ----
            __syncthreads();              // block stores drained to L2
            if (threadIdx.x == 0) {
                __threadfence();          // release: writeback dirty L2 lines
                __hip_atomic_fetch_add(&bar[l], 1u,
                                       __ATOMIC_RELEASE, __HIP_MEMORY_SCOPE_AGENT);
                while (__hip_atomic_load(&bar[l],
                                         __ATOMIC_RELAXED, __HIP_MEMORY_SCOPE_AGENT)
                       < (unsigned)NBLOCKS) { /* tight spin */ }
                __threadfence();          // acquire: invalidate L1/L2
            }
            __syncthreads();              // release whole block
            // ------------------------------------------------------------
        }
        cur = dst;
    }
}

extern "C" void kernel_launch(void* const* d_in, const int* in_sizes, int n_in,
                              void* d_out, int out_size, void* d_ws, size_t ws_size,
                              hipStream_t stream) {
    const float* x = (const float*)d_in[0];   // (1024,)
    const float* P = (const float*)d_in[1];   // (8192, 8193)
    float* out = (float*)d_out;               // (1024,)

    float* ws = (float*)d_ws;                                  // 2*1024 floats
    unsigned int* bar = (unsigned int*)((char*)d_ws + 8192);   // 8 counters

    // zero the barrier counters (stream-ordered; graph-capturable)
    hipMemsetAsync(bar, 0, 8 * sizeof(unsigned int), stream);

    void* args[] = { (void*)&P, (void*)&x, (void*)&out, (void*)&ws, (void*)&bar };
    hipLaunchCooperativeKernel((const void*)mlp_fused_kernel,
                               dim3(NBLOCKS), dim3(TPB), args, 0, stream);
}